// Round 17
// baseline (57.422 us; speedup 1.0000x reference)
//
#include <hip/hip_runtime.h>
#include <hip/hip_bf16.h>

#define LOG2E     1.4426950408889634f
#define TWO_LOG2E 2.8853900817779268f

typedef __attribute__((ext_vector_type(8))) _Float16 f16x8;
typedef __attribute__((ext_vector_type(4))) float    f32x4;
typedef __attribute__((ext_vector_type(2))) float    f32x2;

__device__ __forceinline__ float rcp_(float x){ return __builtin_amdgcn_rcpf(x); }
__device__ __forceinline__ float ex2_(float x){ return __builtin_amdgcn_exp2f(x); }

// quad broadcast: every 4-lane group reads lane K of the group (DPP quad_perm)
template<int K>
__device__ __forceinline__ float quadbc(float v){
  constexpr int ctrl = K * 0x55;   // quad_perm [K,K,K,K]
  return __int_as_float(__builtin_amdgcn_mov_dpp(__float_as_int(v), ctrl, 0xf, 0xf, true));
}

union FragH { f16x8 v; uint32_t w[4]; uint4 u4; };

__device__ __forceinline__ uint32_t pkh(float a, float b){
  union { _Float16 h; uint16_t u; } ca, cb;
  ca.h = (_Float16)a; cb.h = (_Float16)b;
  return (uint32_t)ca.u | ((uint32_t)cb.u << 16);
}
// load 8 floats, exp(), convert to f16x8
__device__ __forceinline__ void exph8(const float* __restrict__ src, FragH& out){
  float4 a = *(const float4*)src;
  float4 b = *(const float4*)(src + 4);
  out.w[0] = pkh(__expf(a.x), __expf(a.y));
  out.w[1] = pkh(__expf(a.z), __expf(a.w));
  out.w[2] = pkh(__expf(b.x), __expf(b.y));
  out.w[3] = pkh(__expf(b.z), __expf(b.w));
}

#define TBL_N     256
#define TBL_SCALE 12.8f          // TBL_N / 20
#define TBL_LO    -10.0f
#define TBL_CMAX  9.9f

// attention inner: 8 threads/b, thread r owns i,j = r*4..r*4+3.
#define EATT_J(JQ, JR) { \
    const float Fj_ = quadbc<JQ>(Fjr[JR]); \
    const float Fq_ = quadbc<JQ>(Fqr[JR]); \
    const float xj_ = quadbc<JQ>(xi[JR]); \
    const f32x2 Fj2_ = {Fj_,Fj_}, Fq2_ = {Fq_,Fq_}, xj2_ = {xj_,xj_}; \
    f32x2 pe_; \
    pe_ = __builtin_elementwise_max(Ei2[0]*Fj2_, Eq2[0]*Fq2_); s2[0] = s2[0] + pe_; sx2[0] = sx2[0] + pe_*xj2_; \
    pe_ = __builtin_elementwise_max(Ei2[1]*Fj2_, Eq2[1]*Fq2_); s2[1] = s2[1] + pe_; sx2[1] = sx2[1] + pe_*xj2_; \
  }
#define EATT_Q(JQ) EATT_J(JQ,0) EATT_J(JQ,1) EATT_J(JQ,2) EATT_J(JQ,3)
#define EATT_ALL   EATT_Q(0) EATT_Q(1) EATT_Q(2) EATT_Q(3)

// single fused kernel: 32 b/block, 256 thr, 2048 blocks, (256,8).
// 8 blocks/CU -> 8 waves/SIMD IF VGPR <= 64 (m69 quantization: 64->8w, 128->4w).
// Phase 0: stage f16 exp(m2w)/exp(m3w) frags + pool constants into LDS.
// Phase 1: u(c) table (1 entry/thread) + attention (8 thr/b, DPP+lane^4).
// Phase 2: pool via table, z_enc; decoder MFMA on waves 0-1 (frags JIT from LDS).
__global__ __launch_bounds__(256, 8) void IDSSM_main(
    const float* __restrict__ xs,  const float* __restrict__ stx,
    const float* __restrict__ Wg,  const float* __restrict__ ag,
    const float* __restrict__ p1w, const float* __restrict__ p1b,
    const float* __restrict__ p2w, const float* __restrict__ p2b,
    const float* __restrict__ m1w, const float* __restrict__ m1b,
    const float* __restrict__ m2w, const float* __restrict__ m2b,
    const float* __restrict__ m3w, const float* __restrict__ m3b,
    float* __restrict__ out, int B)
{
  __shared__ uint4 fgl[768];       // fg1 slots 0-7: [0,512); fg2 slots 0-3: [512,768)
  __shared__ float tbl[TBL_N];     // u(c)*log2e PWL table (1 KB)
  __shared__ float qsh[16], pbb[16], p2wn[16], scal[3];

  const int tid = threadIdx.x;
  const int lb  = tid >> 3;        // local b (0..31)
  const int r   = tid & 7;         // lane-in-b
  const int b0  = blockIdx.x * 32;
  const int b   = b0 + lb;
  const bool valid = (b < B);
  const int rsrc = valid ? b : (B - 1);

  // ---------------- phase 0: own x slice + stage frags/constants -----------
  const float4 xv = *(const float4*)(xs + (size_t)rsrc*32 + r*4);
  float xi[4] = { xv.x, xv.y, xv.z, xv.w };

  // weight fragments: 12 slots x 64 lanes, 3 per thread
  #pragma unroll
  for (int rep = 0; rep < 3; ++rep){
    const int s    = tid + rep*256;
    const int slot = s >> 6;
    const int l    = s & 63;
    const int bl_  = l & 15;
    const int gt_  = l >> 4;
    const float* src;
    if (slot < 8) src = m2w + (bl_ + 16*(slot>>1))*64 + 8*gt_ + 32*(slot&1);
    else { const int s2 = slot - 8;
           src = m3w + (bl_ + 16*(s2>>1))*64 + 8*gt_ + 32*(s2&1); }
    FragH h;
    exph8(src, h);
    fgl[slot*64 + l] = h.u4;
  }
  if (tid >= 64 && tid < 80){
    const int k = tid - 64;
    float acc = 0.f;
    #pragma unroll
    for (int d = 0; d < 32; ++d) acc += p1w[k*32 + d] * Wg[d];
    qsh[k]  = acc * TWO_LOG2E;
    pbb[k]  = p1b[k] * TWO_LOG2E;
    p2wn[k] = -2.f * p2w[k];
  }
  if (tid == 80){
    float A1 = 0.f, A2 = 0.f;
    #pragma unroll
    for (int d = 0; d < 32; ++d){ A1 += Wg[d]*ag[d]; A2 += Wg[d]*ag[32+d]; }
    scal[0] = A1 * LOG2E;
    scal[1] = A2 * LOG2E;
  }
  if (tid == 81){
    float sp = 0.f;
    #pragma unroll
    for (int k = 0; k < 16; ++k) sp += p2w[k];
    scal[2] = sp + p2b[0];
  }
  __syncthreads();     // frags + qs/scal ready

  // ---------------- phase 1: table entry (1/thread) + attention ------------
  {
    const float c = TBL_LO + (float)tid * (1.0f/TBL_SCALE);
    float u = scal[2];
    #pragma unroll
    for (int k = 0; k < 16; ++k){
      float E = ex2_(fmaf(c, qsh[k], pbb[k]));
      u = fmaf(p2wn[k], rcp_(E + 1.f), u);
    }
    tbl[tid] = u * LOG2E;
  }

  const float A1p = scal[0], A2p = scal[1];
  float Fjr[4], Fqr[4];
  #pragma unroll
  for (int t = 0; t < 4; ++t){
    const float tv = A2p * xi[t];
    Fjr[t] = ex2_(tv);
    Fqr[t] = ex2_(0.2f * tv);
  }
  f32x2 Ei2[2], Eq2[2], s2[2], sx2[2];
  #pragma unroll
  for (int p = 0; p < 2; ++p){
    const float sa = A1p * xi[2*p], sb = A1p * xi[2*p + 1];
    Ei2[p] = (f32x2){ ex2_(sa), ex2_(sb) };
    Eq2[p] = (f32x2){ ex2_(0.2f*sa), ex2_(0.2f*sb) };
    s2[p]  = (f32x2)(0.f);
    sx2[p] = (f32x2)(0.f);
  }
  EATT_ALL                       // 16 j's of own quad
  // swap to other quad's data in place
  #pragma unroll
  for (int t = 0; t < 4; ++t){
    xi[t]  = __shfl_xor(xi[t], 4);
    Fjr[t] = __shfl_xor(Fjr[t], 4);
    Fqr[t] = __shfl_xor(Fqr[t], 4);
  }
  EATT_ALL                       // 16 j's of other quad

  __syncthreads();     // table ready

  // ---------------- phase 2: pooling + z_enc ----------------
  float Zs = 0.f, Zd = 0.f;
  #pragma unroll
  for (int p = 0; p < 2; ++p){
    #pragma unroll
    for (int h = 0; h < 2; ++h){
      const float sv  = h ? s2[p].y  : s2[p].x;
      const float sxv = h ? sx2[p].y : sx2[p].x;
      const float c  = sxv * rcp_(sv);
      const float cc = fminf(fmaxf(c, TBL_LO), TBL_CMAX);
      const float f  = (cc - TBL_LO) * TBL_SCALE;
      const int   n  = (int)f;
      const float fr = f - (float)n;
      const float t0 = tbl[n];
      const float t1 = tbl[n + 1];
      const float eb = ex2_(fmaf(fr, t1 - t0, t0));
      Zs = fmaf(eb, c, Zs);
      Zd += eb;
    }
  }
  Zs += __shfl_xor(Zs, 1);  Zd += __shfl_xor(Zd, 1);
  Zs += __shfl_xor(Zs, 2);  Zd += __shfl_xor(Zd, 2);
  Zs += __shfl_xor(Zs, 4);  Zd += __shfl_xor(Zd, 4);
  const float Z = Zs * rcp_(Zd);

  if (valid){
    const float4 w = ((const float4*)Wg)[r];
    *(float4*)(out + (size_t)b*32 + r*4) =
        make_float4(Z*w.x, Z*w.y, Z*w.z, Z*w.w);
  }

  // ========== decoder (MFMA f16, frags JIT from LDS): waves 0-1 ==========
  const int wv = tid >> 6;
  if (wv >= 2) return;             // no barriers after this point

  const int lane = tid & 63;
  const int gt   = lane >> 4;
  const int bl   = lane & 15;
  const int bd   = b0 + wv*16 + bl;
  const float sx0 = stx[(bd < B) ? bd : (B-1)];

  // h1 in f16 B-fragment layout: lane owns b=bl, g=8*gt+j+32*kt
  FragH h1f[2];
  #pragma unroll
  for (int kt = 0; kt < 2; ++kt){
    const int g0 = 8*gt + 32*kt;
    const float4* w1p = (const float4*)(m1w + g0);
    const float4* b1p = (const float4*)(m1b + g0);
    float4 wa = w1p[0], wb = w1p[1];
    float4 ba = b1p[0], bb = b1p[1];
    float wv8[8] = { wa.x,wa.y,wa.z,wa.w, wb.x,wb.y,wb.z,wb.w };
    float bv8[8] = { ba.x,ba.y,ba.z,ba.w, bb.x,bb.y,bb.z,bb.w };
    float hv[8];
    #pragma unroll
    for (int j = 0; j < 8; ++j){
      const float e1 = ex2_(wv8[j] * LOG2E) * TWO_LOG2E;   // exp(m1w)*2log2e
      const float E  = ex2_(fmaf(sx0, e1, bv8[j] * TWO_LOG2E));
      hv[j] = fmaf(-2.f, rcp_(E + 1.f), 1.f);              // tanh
    }
    #pragma unroll
    for (int jw = 0; jw < 4; ++jw)
      h1f[kt].w[jw] = pkh(hv[2*jw], hv[2*jw+1]);
  }

  // GEMM1 (f16): H2pre^T[h][b] = sum_g exp(m2w[h][g]) * h1[b][g] + m2b[h]
  f32x4 acc[4];
  #pragma unroll
  for (int mt = 0; mt < 4; ++mt){
    float4 bi = *(const float4*)(m2b + 16*mt + 4*gt);
    acc[mt][0]=bi.x; acc[mt][1]=bi.y; acc[mt][2]=bi.z; acc[mt][3]=bi.w;
  }
  #pragma unroll
  for (int mt = 0; mt < 4; ++mt){
    #pragma unroll
    for (int kt = 0; kt < 2; ++kt){
      FragH A; A.u4 = fgl[(mt*2 + kt)*64 + lane];   // ds_read_b128, JIT
      acc[mt] = __builtin_amdgcn_mfma_f32_16x16x32_f16(A.v, h1f[kt].v, acc[mt], 0, 0, 0);
    }
  }

  // tanh + f16 pack: lane holds H2^T[h=16mt+4gt+r][b=bl]
  uint32_t Wp[4][2];
  #pragma unroll
  for (int mt = 0; mt < 4; ++mt){
    float t0 = fmaf(-2.f, rcp_(ex2_(acc[mt][0]*TWO_LOG2E) + 1.f), 1.f);
    float t1 = fmaf(-2.f, rcp_(ex2_(acc[mt][1]*TWO_LOG2E) + 1.f), 1.f);
    float t2 = fmaf(-2.f, rcp_(ex2_(acc[mt][2]*TWO_LOG2E) + 1.f), 1.f);
    float t3 = fmaf(-2.f, rcp_(ex2_(acc[mt][3]*TWO_LOG2E) + 1.f), 1.f);
    Wp[mt][0] = pkh(t0, t1);
    Wp[mt][1] = pkh(t2, t3);
  }

  // cross-lane transpose into f16 B-fragment layout for GEMM2:
  //   dest lane needs h = 8*gt + j + 32*kt2 at b=bl; word jw (h-pair):
  //   src_lane = bl + 16*(((jw>>1) + 2*gt)&3), src word = Wp[2*kt2 + (gt>>1)][jw&1]
  FragH B2[2];
  const int hiSel = gt >> 1;
  #pragma unroll
  for (int kt2 = 0; kt2 < 2; ++kt2){
    #pragma unroll
    for (int jw = 0; jw < 4; ++jw){
      const int sl = bl + 16*(((jw>>1) + 2*gt) & 3);
      const int w  = jw & 1;
      uint32_t c0 = (uint32_t)__shfl((int)Wp[2*kt2+0][w], sl);
      uint32_t c1 = (uint32_t)__shfl((int)Wp[2*kt2+1][w], sl);
      B2[kt2].w[jw] = hiSel ? c1 : c0;
    }
  }

  // GEMM2 (f16): Z^T[d][b] = sum_h exp(m3w[d][h]) * H2[b][h] + m3b[d]
  f32x4 acc2[2];
  #pragma unroll
  for (int mt2 = 0; mt2 < 2; ++mt2){
    float4 bi = *(const float4*)(m3b + 16*mt2 + 4*gt);
    acc2[mt2][0]=bi.x; acc2[mt2][1]=bi.y; acc2[mt2][2]=bi.z; acc2[mt2][3]=bi.w;
  }
  #pragma unroll
  for (int mt2 = 0; mt2 < 2; ++mt2){
    #pragma unroll
    for (int kt2 = 0; kt2 < 2; ++kt2){
      FragH A; A.u4 = fgl[512 + (mt2*2 + kt2)*64 + lane];  // ds_read_b128, JIT
      acc2[mt2] = __builtin_amdgcn_mfma_f32_16x16x32_f16(A.v, B2[kt2].v, acc2[mt2], 0, 0, 0);
    }
  }

  if (bd < B){
    float* o = out + (size_t)B*32 + (size_t)bd*32;
    *(float4*)(o + 4*gt)      = make_float4(acc2[0][0], acc2[0][1], acc2[0][2], acc2[0][3]);
    *(float4*)(o + 16 + 4*gt) = make_float4(acc2[1][0], acc2[1][1], acc2[1][2], acc2[1][3]);
  }
}

extern "C" void kernel_launch(void* const* d_in, const int* in_sizes, int n_in,
                              void* d_out, int out_size, void* d_ws, size_t ws_size,
                              hipStream_t stream)
{
  const float* xs  = (const float*)d_in[0];
  const float* stx = (const float*)d_in[1];
  const float* Wg  = (const float*)d_in[2];
  const float* ag  = (const float*)d_in[3];
  const float* p1w = (const float*)d_in[4];
  const float* p1b = (const float*)d_in[5];
  const float* p2w = (const float*)d_in[6];
  const float* p2b = (const float*)d_in[7];
  const float* m1w = (const float*)d_in[8];
  const float* m1b = (const float*)d_in[9];
  const float* m2w = (const float*)d_in[10];
  const float* m2b = (const float*)d_in[11];
  const float* m3w = (const float*)d_in[12];
  const float* m3b = (const float*)d_in[13];
  float* out = (float*)d_out;
  const int B = in_sizes[0] / 32;
  const int nblk = (B + 31) / 32;
  hipLaunchKernelGGL(IDSSM_main, dim3(nblk), dim3(256), 0, stream,
                     xs, stx, Wg, ag, p1w, p1b, p2w, p2b,
                     m1w, m1b, m2w, m2b, m3w, m3b, out, B);
}

// Round 18
// 24.167 us; speedup vs baseline: 2.3760x; 2.3760x over previous
//
#include <hip/hip_runtime.h>
#include <hip/hip_bf16.h>

#define LOG2E     1.4426950408889634f
#define TWO_LOG2E 2.8853900817779268f

typedef __attribute__((ext_vector_type(8))) _Float16 f16x8;
typedef __attribute__((ext_vector_type(4))) float    f32x4;
typedef __attribute__((ext_vector_type(2))) float    f32x2;

__device__ __forceinline__ float rcp_(float x){ return __builtin_amdgcn_rcpf(x); }
__device__ __forceinline__ float ex2_(float x){ return __builtin_amdgcn_exp2f(x); }

// quad broadcast: every 4-lane group reads lane K of the group (DPP quad_perm)
template<int K>
__device__ __forceinline__ float quadbc(float v){
  constexpr int ctrl = K * 0x55;   // quad_perm [K,K,K,K]
  return __int_as_float(__builtin_amdgcn_mov_dpp(__float_as_int(v), ctrl, 0xf, 0xf, true));
}

union FragH { f16x8 v; uint32_t w[4]; uint4 u4; };

__device__ __forceinline__ uint32_t pkh(float a, float b){
  union { _Float16 h; uint16_t u; } ca, cb;
  ca.h = (_Float16)a; cb.h = (_Float16)b;
  return (uint32_t)ca.u | ((uint32_t)cb.u << 16);
}
// load 8 floats, exp(), convert to f16x8
__device__ __forceinline__ void exph8(const float* __restrict__ src, FragH& out){
  float4 a = *(const float4*)src;
  float4 b = *(const float4*)(src + 4);
  out.w[0] = pkh(__expf(a.x), __expf(a.y));
  out.w[1] = pkh(__expf(a.z), __expf(a.w));
  out.w[2] = pkh(__expf(b.x), __expf(b.y));
  out.w[3] = pkh(__expf(b.z), __expf(b.w));
}

#define TBL_N     256
#define TBL_SCALE 12.8f          // TBL_N / 20
#define TBL_LO    -10.0f
#define TBL_CMAX  9.9f

// attention inner: 4 threads/b, thread q owns i,j = q*8..q*8+7.
// Fj, Fq, xj all quad-broadcast from the owning lane (no x-row array).
#define ATT_J(JQ, JR) { \
    const float Fj_ = quadbc<JQ>(Fjr[JR]); \
    const float Fq_ = quadbc<JQ>(Fqr[JR]); \
    const float xj_ = quadbc<JQ>(xi[JR]); \
    const f32x2 Fj2_ = {Fj_,Fj_}, Fq2_ = {Fq_,Fq_}, xj2_ = {xj_,xj_}; \
    f32x2 pe_; \
    pe_ = __builtin_elementwise_max(Ei2[0]*Fj2_, Eq2[0]*Fq2_); s2[0] = s2[0] + pe_; sx2[0] = sx2[0] + pe_*xj2_; \
    pe_ = __builtin_elementwise_max(Ei2[1]*Fj2_, Eq2[1]*Fq2_); s2[1] = s2[1] + pe_; sx2[1] = sx2[1] + pe_*xj2_; \
    pe_ = __builtin_elementwise_max(Ei2[2]*Fj2_, Eq2[2]*Fq2_); s2[2] = s2[2] + pe_; sx2[2] = sx2[2] + pe_*xj2_; \
    pe_ = __builtin_elementwise_max(Ei2[3]*Fj2_, Eq2[3]*Fq2_); s2[3] = s2[3] + pe_; sx2[3] = sx2[3] + pe_*xj2_; \
  }
#define ATT_Q(JQ) ATT_J(JQ,0) ATT_J(JQ,1) ATT_J(JQ,2) ATT_J(JQ,3) \
                  ATT_J(JQ,4) ATT_J(JQ,5) ATT_J(JQ,6) ATT_J(JQ,7)

// single fused kernel: 64 b/block, 256 thr, 1024 blocks, (256,4).
// Phase 0: stage frags (f16 exp(m2w)/exp(m3w)) + pool constants into LDS.
// Phase 1: build u(c) table (1 entry/thread) + attention (regs, DPP-shared).
// Phase 2: pool via table, z_enc, decoder MFMA (frags JIT from LDS).
__global__ __launch_bounds__(256, 4) void IDSSM_main(
    const float* __restrict__ xs,  const float* __restrict__ stx,
    const float* __restrict__ Wg,  const float* __restrict__ ag,
    const float* __restrict__ p1w, const float* __restrict__ p1b,
    const float* __restrict__ p2w, const float* __restrict__ p2b,
    const float* __restrict__ m1w, const float* __restrict__ m1b,
    const float* __restrict__ m2w, const float* __restrict__ m2b,
    const float* __restrict__ m3w, const float* __restrict__ m3b,
    float* __restrict__ out, int B)
{
  __shared__ uint4 fgl[768];       // fg1 slots 0-7: [0,512); fg2 slots 0-3: [512,768)
  __shared__ float tbl[TBL_N];     // u(c)*log2e PWL table (1 KB)
  __shared__ float qsh[16], pbb[16], p2wn[16], scal[3];

  const int tid = threadIdx.x;
  const int lb  = tid >> 2;        // local b (0..63)
  const int q   = tid & 3;         // quarter
  const int b0  = blockIdx.x * 64;
  const int b   = b0 + lb;
  const bool valid = (b < B);
  const int rsrc = valid ? b : (B - 1);

  // ---------------- phase 0: own x slice + stage frags/constants -----------
  // own 8 x values: 32B/thread, quad covers the full 128B row (coalesced)
  const float4* xrow4 = (const float4*)(xs + (size_t)rsrc*32);
  const float4 xia = xrow4[q*2], xib = xrow4[q*2 + 1];
  float xi[8] = { xia.x, xia.y, xia.z, xia.w, xib.x, xib.y, xib.z, xib.w };

  // weight fragments: 12 slots x 64 lanes, 3 per thread
  #pragma unroll
  for (int rep = 0; rep < 3; ++rep){
    const int s    = tid + rep*256;
    const int slot = s >> 6;
    const int l    = s & 63;
    const int bl_  = l & 15;
    const int gt_  = l >> 4;
    const float* src;
    if (slot < 8) src = m2w + (bl_ + 16*(slot>>1))*64 + 8*gt_ + 32*(slot&1);
    else { const int s2 = slot - 8;
           src = m3w + (bl_ + 16*(s2>>1))*64 + 8*gt_ + 32*(s2&1); }
    FragH h;
    exph8(src, h);
    fgl[slot*64 + l] = h.u4;
  }
  if (tid >= 64 && tid < 80){
    const int k = tid - 64;
    float acc = 0.f;
    #pragma unroll
    for (int d = 0; d < 32; ++d) acc += p1w[k*32 + d] * Wg[d];
    qsh[k]  = acc * TWO_LOG2E;
    pbb[k]  = p1b[k] * TWO_LOG2E;
    p2wn[k] = -2.f * p2w[k];
  }
  if (tid == 80){
    float A1 = 0.f, A2 = 0.f;
    #pragma unroll
    for (int d = 0; d < 32; ++d){ A1 += Wg[d]*ag[d]; A2 += Wg[d]*ag[32+d]; }
    scal[0] = A1 * LOG2E;
    scal[1] = A2 * LOG2E;
  }
  if (tid == 81){
    float sp = 0.f;
    #pragma unroll
    for (int k = 0; k < 16; ++k) sp += p2w[k];
    scal[2] = sp + p2b[0];
  }
  __syncthreads();     // frags + qs/scal ready

  // ---------------- phase 1: table entry (1/thread) + attention ------------
  {
    const float c = TBL_LO + (float)tid * (1.0f/TBL_SCALE);
    float u = scal[2];
    #pragma unroll
    for (int k = 0; k < 16; ++k){
      float E = ex2_(fmaf(c, qsh[k], pbb[k]));
      u = fmaf(p2wn[k], rcp_(E + 1.f), u);
    }
    tbl[tid] = u * LOG2E;
  }

  const float A1p = scal[0], A2p = scal[1];
  float Fjr[8], Fqr[8];
  #pragma unroll
  for (int t = 0; t < 8; ++t){
    const float tv = A2p * xi[t];
    Fjr[t] = ex2_(tv);
    Fqr[t] = ex2_(0.2f * tv);
  }
  f32x2 Ei2[4], Eq2[4], s2[4], sx2[4];
  #pragma unroll
  for (int p = 0; p < 4; ++p){
    const float sa = A1p * xi[2*p], sb = A1p * xi[2*p + 1];
    Ei2[p] = (f32x2){ ex2_(sa), ex2_(sb) };
    Eq2[p] = (f32x2){ ex2_(0.2f*sa), ex2_(0.2f*sb) };
    s2[p]  = (f32x2)(0.f);
    sx2[p] = (f32x2)(0.f);
  }
  ATT_Q(0) ATT_Q(1) ATT_Q(2) ATT_Q(3)

  __syncthreads();     // table ready

  // ---------------- phase 2: pooling + z_enc ----------------
  float Zs = 0.f, Zd = 0.f;
  #pragma unroll
  for (int p = 0; p < 4; ++p){
    #pragma unroll
    for (int h = 0; h < 2; ++h){
      const float sv  = h ? s2[p].y  : s2[p].x;
      const float sxv = h ? sx2[p].y : sx2[p].x;
      const float c  = sxv * rcp_(sv);
      const float cc = fminf(fmaxf(c, TBL_LO), TBL_CMAX);
      const float f  = (cc - TBL_LO) * TBL_SCALE;
      const int   n  = (int)f;
      const float fr = f - (float)n;
      const float t0 = tbl[n];
      const float t1 = tbl[n + 1];
      const float eb = ex2_(fmaf(fr, t1 - t0, t0));
      Zs = fmaf(eb, c, Zs);
      Zd += eb;
    }
  }
  Zs += __shfl_xor(Zs, 1);  Zd += __shfl_xor(Zd, 1);
  Zs += __shfl_xor(Zs, 2);  Zd += __shfl_xor(Zd, 2);
  const float Z = Zs * rcp_(Zd);

  if (valid){
    const float4 w0 = ((const float4*)Wg)[q*2 + 0];
    const float4 w1 = ((const float4*)Wg)[q*2 + 1];
    float4* o = (float4*)(out + (size_t)b*32 + q*8);
    o[0] = make_float4(Z*w0.x, Z*w0.y, Z*w0.z, Z*w0.w);
    o[1] = make_float4(Z*w1.x, Z*w1.y, Z*w1.z, Z*w1.w);
  }

  // ========== decoder (MFMA f16, frags JIT from LDS, e1 inline) ==========
  const int lane = tid & 63;
  const int wv   = tid >> 6;
  const int gt   = lane >> 4;
  const int bl   = lane & 15;
  const int bd   = b0 + wv*16 + bl;
  const float sx0 = stx[(bd < B) ? bd : (B-1)];

  // h1 in f16 B-fragment layout: lane owns b=bl, g=8*gt+j+32*kt
  FragH h1f[2];
  #pragma unroll
  for (int kt = 0; kt < 2; ++kt){
    const int g0 = 8*gt + 32*kt;
    const float4* w1p = (const float4*)(m1w + g0);
    const float4* b1p = (const float4*)(m1b + g0);
    float4 wa = w1p[0], wb = w1p[1];
    float4 ba = b1p[0], bb = b1p[1];
    float wv8[8] = { wa.x,wa.y,wa.z,wa.w, wb.x,wb.y,wb.z,wb.w };
    float bv8[8] = { ba.x,ba.y,ba.z,ba.w, bb.x,bb.y,bb.z,bb.w };
    float hv[8];
    #pragma unroll
    for (int j = 0; j < 8; ++j){
      const float e1 = ex2_(wv8[j] * LOG2E) * TWO_LOG2E;   // exp(m1w)*2log2e
      const float E  = ex2_(fmaf(sx0, e1, bv8[j] * TWO_LOG2E));
      hv[j] = fmaf(-2.f, rcp_(E + 1.f), 1.f);              // tanh
    }
    #pragma unroll
    for (int jw = 0; jw < 4; ++jw)
      h1f[kt].w[jw] = pkh(hv[2*jw], hv[2*jw+1]);
  }

  // GEMM1 (f16): H2pre^T[h][b] = sum_g exp(m2w[h][g]) * h1[b][g] + m2b[h]
  f32x4 acc[4];
  #pragma unroll
  for (int mt = 0; mt < 4; ++mt){
    float4 bi = *(const float4*)(m2b + 16*mt + 4*gt);
    acc[mt][0]=bi.x; acc[mt][1]=bi.y; acc[mt][2]=bi.z; acc[mt][3]=bi.w;
  }
  #pragma unroll
  for (int mt = 0; mt < 4; ++mt){
    #pragma unroll
    for (int kt = 0; kt < 2; ++kt){
      FragH A; A.u4 = fgl[(mt*2 + kt)*64 + lane];   // ds_read_b128, JIT
      acc[mt] = __builtin_amdgcn_mfma_f32_16x16x32_f16(A.v, h1f[kt].v, acc[mt], 0, 0, 0);
    }
  }

  // tanh + f16 pack: lane holds H2^T[h=16mt+4gt+r][b=bl]
  uint32_t Wp[4][2];
  #pragma unroll
  for (int mt = 0; mt < 4; ++mt){
    float t0 = fmaf(-2.f, rcp_(ex2_(acc[mt][0]*TWO_LOG2E) + 1.f), 1.f);
    float t1 = fmaf(-2.f, rcp_(ex2_(acc[mt][1]*TWO_LOG2E) + 1.f), 1.f);
    float t2 = fmaf(-2.f, rcp_(ex2_(acc[mt][2]*TWO_LOG2E) + 1.f), 1.f);
    float t3 = fmaf(-2.f, rcp_(ex2_(acc[mt][3]*TWO_LOG2E) + 1.f), 1.f);
    Wp[mt][0] = pkh(t0, t1);
    Wp[mt][1] = pkh(t2, t3);
  }

  // cross-lane transpose into f16 B-fragment layout for GEMM2:
  //   dest lane needs h = 8*gt + j + 32*kt2 at b=bl; word jw (h-pair):
  //   src_lane = bl + 16*(((jw>>1) + 2*gt)&3), src word = Wp[2*kt2 + (gt>>1)][jw&1]
  FragH B2[2];
  const int hiSel = gt >> 1;
  #pragma unroll
  for (int kt2 = 0; kt2 < 2; ++kt2){
    #pragma unroll
    for (int jw = 0; jw < 4; ++jw){
      const int sl = bl + 16*(((jw>>1) + 2*gt) & 3);
      const int w  = jw & 1;
      uint32_t c0 = (uint32_t)__shfl((int)Wp[2*kt2+0][w], sl);
      uint32_t c1 = (uint32_t)__shfl((int)Wp[2*kt2+1][w], sl);
      B2[kt2].w[jw] = hiSel ? c1 : c0;
    }
  }

  // GEMM2 (f16): Z^T[d][b] = sum_h exp(m3w[d][h]) * H2[b][h] + m3b[d]
  f32x4 acc2[2];
  #pragma unroll
  for (int mt2 = 0; mt2 < 2; ++mt2){
    float4 bi = *(const float4*)(m3b + 16*mt2 + 4*gt);
    acc2[mt2][0]=bi.x; acc2[mt2][1]=bi.y; acc2[mt2][2]=bi.z; acc2[mt2][3]=bi.w;
  }
  #pragma unroll
  for (int mt2 = 0; mt2 < 2; ++mt2){
    #pragma unroll
    for (int kt2 = 0; kt2 < 2; ++kt2){
      FragH A; A.u4 = fgl[512 + (mt2*2 + kt2)*64 + lane];  // ds_read_b128, JIT
      acc2[mt2] = __builtin_amdgcn_mfma_f32_16x16x32_f16(A.v, B2[kt2].v, acc2[mt2], 0, 0, 0);
    }
  }

  if (bd < B){
    float* o = out + (size_t)B*32 + (size_t)bd*32;
    *(float4*)(o + 4*gt)      = make_float4(acc2[0][0], acc2[0][1], acc2[0][2], acc2[0][3]);
    *(float4*)(o + 16 + 4*gt) = make_float4(acc2[1][0], acc2[1][1], acc2[1][2], acc2[1][3]);
  }
}

extern "C" void kernel_launch(void* const* d_in, const int* in_sizes, int n_in,
                              void* d_out, int out_size, void* d_ws, size_t ws_size,
                              hipStream_t stream)
{
  const float* xs  = (const float*)d_in[0];
  const float* stx = (const float*)d_in[1];
  const float* Wg  = (const float*)d_in[2];
  const float* ag  = (const float*)d_in[3];
  const float* p1w = (const float*)d_in[4];
  const float* p1b = (const float*)d_in[5];
  const float* p2w = (const float*)d_in[6];
  const float* p2b = (const float*)d_in[7];
  const float* m1w = (const float*)d_in[8];
  const float* m1b = (const float*)d_in[9];
  const float* m2w = (const float*)d_in[10];
  const float* m2b = (const float*)d_in[11];
  const float* m3w = (const float*)d_in[12];
  const float* m3b = (const float*)d_in[13];
  float* out = (float*)d_out;
  const int B = in_sizes[0] / 32;
  const int nblk = (B + 63) / 64;
  hipLaunchKernelGGL(IDSSM_main, dim3(nblk), dim3(256), 0, stream,
                     xs, stx, Wg, ag, p1w, p1b, p2w, p2b,
                     m1w, m1b, m2w, m2b, m3w, m3b, out, B);
}